// Round 10
// baseline (775.504 us; speedup 1.0000x reference)
//
#include <hip/hip_runtime.h>

#define N_TOK  65536
#define N_CODE 8192
#define DIM    256

typedef _Float16 f16;
typedef _Float16 f16x8 __attribute__((ext_vector_type(8)));
typedef float    f32x4 __attribute__((ext_vector_type(4)));

// ---------- kernel 1: row sum-of-squares (one wave per row) ----------
// Used for W -> esq only (X's row-sums are fused into argmin, v12).
// NOTE: summation order (float4 sequential + shfl_down tree) bit-matches the
// reference fp32 reduction — do not change.
__global__ __launch_bounds__(256) void rowsq_kernel(const float* __restrict__ src,
                                                    float* __restrict__ dst, int nrows) {
    int row  = blockIdx.x * 4 + (threadIdx.x >> 6);
    int lane = threadIdx.x & 63;
    if (row >= nrows) return;
    float4 v = ((const float4*)(src + (size_t)row * DIM))[lane];
    float s = v.x * v.x + v.y * v.y + v.z * v.z + v.w * v.w;
#pragma unroll
    for (int off = 32; off; off >>= 1) s += __shfl_down(s, off, 64);
    if (lane == 0) dst[row] = s;
}

// ---------- kernel 2: split W into 2 fp16 limbs, TRANSPOSED (k-major) ----------
// W1t/W2t layout: 16B granule (o, c) at byte o*131072 + c*16 holds
// W?[c][o*8 .. o*8+7]  (o = dim-octet 0..31, c = code 0..8191).
__global__ __launch_bounds__(256) void splitw_t_kernel(const float* __restrict__ W,
                                                       f16* __restrict__ W1t,
                                                       f16* __restrict__ W2t) {
    int g = blockIdx.x * 256 + threadIdx.x;   // octet-task id, < 32*8192
    int o = g >> 13;                          // dim octet 0..31
    int c = g & 8191;                         // code
    const float* p = W + (size_t)c * DIM + o * 8;
    float4 v0 = ((const float4*)p)[0];
    float4 v1 = ((const float4*)p)[1];
    float e[8] = {v0.x, v0.y, v0.z, v0.w, v1.x, v1.y, v1.z, v1.w};
    union { f16 h[8]; uint4 u; } p1, p2;
#pragma unroll
    for (int i = 0; i < 8; ++i) {
        float ws = e[i] * 16384.0f;                  // exact (pow2)
        f16 w1 = (f16)ws;                            // RNE
        float r = (ws - (float)w1) * 2048.0f;        // exact
        p1.h[i] = w1; p2.h[i] = (f16)r;
    }
    size_t byteoff = (size_t)o * 131072 + (size_t)c * 16;
    *(uint4*)((char*)W1t + byteoff) = p1.u;
    *(uint4*)((char*)W2t + byteoff) = p2.u;
}

// ---------- kernel 3: fused MFMA GEMM + argmin, v12 ----------
// v8 body verbatim (639us, best of family: v9 domains / v10-v11 epilogue
// interleave all null-to-negative -> the ~37% MFMA-idle is intrinsic to the
// 2-waves/SIMD 2-block structure; MFMA floor of the 3-limb-pass scheme is
// ~398us and needs a different schedule family to approach).
// v12 changes (safe):
//  - FUSED sxq: X row-sums computed in-kernel from the already-loaded A data,
//    reproducing rowsq's exact tree: quad l = s*8+q*2+h, stages 32/16/8 are
//    s-pairs (intra-lane), 4/2 are q (cross-lane), 1 is h. Saves the 67MB
//    rowsq(X) pass (~12us).
//  - Z-seed: s=0 MFMA uses C=0 operand (exact; deletes 32 movs/tile).
__global__ __launch_bounds__(256, 2) void argmin_mfma12(
    const float* __restrict__ X, const f16* __restrict__ W1t, const f16* __restrict__ W2t,
    const float* __restrict__ esq, int* __restrict__ out_idx) {

    __shared__ char wbuf[65536];   // [sel:2][limb:2][o:32][c:32]*16B

    const int tid  = threadIdx.x;
    const int lane = tid & 63;
    const int wv   = tid >> 6;        // 0..3
    const int cl   = lane & 15;       // code-col / token-row within 16
    const int q    = lane >> 4;       // 0..3 k-octet
    const int l5   = lane >> 5;       // 0..1
    const int lane31 = lane & 31;
    const int wavetok0 = blockIdx.x * 128 + wv * 32;

    // ---- A: load 32 tokens x 256 dims, split to 2 f16 limbs, keep in regs.
    // Simultaneously accumulate rowsq partials: P[s][h] = sum of 4 squares of
    // quad (s*8 + q*2 + h) in rowsq's per-lane order.
    f16x8 a1[2][8], a2[2][8];
    float t3[2][2];
#pragma unroll
    for (int mt = 0; mt < 2; ++mt) {
        float P0[8], P1[8];
#pragma unroll
        for (int s = 0; s < 8; ++s) {
            const float* p = X + (size_t)(wavetok0 + mt * 16 + cl) * DIM + s * 32 + q * 8;
            float4 v0 = ((const float4*)p)[0];
            float4 v1 = ((const float4*)p)[1];
            float e[8] = {v0.x, v0.y, v0.z, v0.w, v1.x, v1.y, v1.z, v1.w};
            P0[s] = e[0] * e[0] + e[1] * e[1] + e[2] * e[2] + e[3] * e[3];
            P1[s] = e[4] * e[4] + e[5] * e[5] + e[6] * e[6] + e[7] * e[7];
#pragma unroll
            for (int j = 0; j < 8; ++j) {
                f16 h = (f16)e[j];
                float r = (e[j] - (float)h) * 2048.0f;   // exact
                a1[mt][s][j] = h;
                a2[mt][s][j] = (f16)r;
            }
        }
        // stages off=32,16,8 of the rowsq tree (s-bit combines, intra-lane)
        t3[mt][0] = ((P0[0] + P0[4]) + (P0[2] + P0[6])) + ((P0[1] + P0[5]) + (P0[3] + P0[7]));
        t3[mt][1] = ((P1[0] + P1[4]) + (P1[2] + P1[6])) + ((P1[1] + P1[5]) + (P1[3] + P1[7]));
    }

    // stages off=4,2 (q, cross-lane) and off=1 (h): redistribute so this lane
    // holds sx for its C-fragment tokens mt*16 + q*4 + r. Operand order
    // matches shfl_down exactly: ((q0+q2)+(q1+q3)) per h, then h0+h1.
    float sxr[8];
#pragma unroll
    for (int mt = 0; mt < 2; ++mt)
#pragma unroll
        for (int r = 0; r < 4; ++r) {
            int c = q * 4 + r;
            float h0 = (__shfl(t3[mt][0], c) + __shfl(t3[mt][0], c + 32))
                     + (__shfl(t3[mt][0], c + 16) + __shfl(t3[mt][0], c + 48));
            float h1 = (__shfl(t3[mt][1], c) + __shfl(t3[mt][1], c + 32))
                     + (__shfl(t3[mt][1], c + 16) + __shfl(t3[mt][1], c + 48));
            sxr[mt * 4 + r] = h0 + h1;
        }

    float bestd[8];
    int   besti[8];
#pragma unroll
    for (int i = 0; i < 8; ++i) { bestd[i] = 3.4e38f; besti[i] = 0x7fffffff; }

    // ---- per-lane address constants ----
    const int SLB = l5 * 131072 + lane31 * 16;     // staging source lane part
    const char* RB = wbuf + q * 512 + cl * 16;     // read base (o=s*4+q, c=cl)

    // ---- staging: 32KB per ct (2 limbs x 32 octet-slabs x 512B), 32 wave-
    // instrs, 8/wave. instr fi = wv*8+t: L = fi>>4, octet pair op = fi&15.
    auto stage = [&](int ct2, int sel) {
        const char* g1 = (const char*)W1t + ct2 * 512 + SLB;
        const char* g2 = (const char*)W2t + ct2 * 512 + SLB;
#pragma unroll
        for (int t = 0; t < 8; ++t) {
            int fi = wv * 8 + t;
            int L  = fi >> 4;             // limb (wave-uniform)
            int op = fi & 15;             // octet pair (wave-uniform)
            const char* gsrc = (L ? g2 : g1) + op * 262144;
            char* ldst = wbuf + sel * 32768 + L * 16384 + op * 1024;
            __builtin_amdgcn_global_load_lds(
                (const __attribute__((address_space(1))) unsigned int*)gsrc,
                (__attribute__((address_space(3))) unsigned int*)ldst, 16, 0, 0);
        }
    };

    stage(0, 0);
    __syncthreads();

    const f32x4 Z = (f32x4){0.f, 0.f, 0.f, 0.f};

    for (int ct = 0; ct < N_CODE / 32; ++ct) {
        if (ct + 1 < N_CODE / 32) stage(ct + 1, (ct + 1) & 1);

        float se0 = esq[ct * 32 + cl];
        float se1 = esq[ct * 32 + 16 + cl];

        f32x4 mainA[2][2], cross[2][2];

        const char* va = RB + ((ct & 1) << 15);
#pragma unroll
        for (int s = 0; s < 8; ++s) {
            // all 4 fragments: one vaddr + compile-time immediates
            f16x8 b1[2], b2[2];
            b1[0] = *(const f16x8*)(va + s * 2048);
            b1[1] = *(const f16x8*)(va + s * 2048 + 256);
            b2[0] = *(const f16x8*)(va + s * 2048 + 16384);
            b2[1] = *(const f16x8*)(va + s * 2048 + 16640);
            __builtin_amdgcn_s_setprio(1);
#pragma unroll
            for (int mt = 0; mt < 2; ++mt)
#pragma unroll
                for (int nt = 0; nt < 2; ++nt) {
                    mainA[mt][nt] = __builtin_amdgcn_mfma_f32_16x16x32_f16(
                        a1[mt][s], b1[nt], s ? mainA[mt][nt] : Z, 0, 0, 0);
                    cross[mt][nt] = __builtin_amdgcn_mfma_f32_16x16x32_f16(
                        a2[mt][s], b1[nt], s ? cross[mt][nt] : Z, 0, 0, 0);
                    cross[mt][nt] = __builtin_amdgcn_mfma_f32_16x16x32_f16(
                        a1[mt][s], b2[nt], cross[mt][nt], 0, 0, 0);
                }
            __builtin_amdgcn_s_setprio(0);
        }

        // epilogue: d = fl(fl(sx+se) - 2*dot); dot*2^14 = main + 2^-11*cross
        // per lane, candidates ascend in code (nt inner, ct outer): strict < keeps lowest.
#pragma unroll
        for (int mt = 0; mt < 2; ++mt)
#pragma unroll
            for (int nt = 0; nt < 2; ++nt)
#pragma unroll
                for (int r = 0; r < 4; ++r) {
                    float mc = fmaf(cross[mt][nt][r], 4.8828125e-4f, mainA[mt][nt][r]);  // *2^-11
                    float t1 = sxr[mt * 4 + r] + (nt ? se1 : se0);
                    float d  = fmaf(-1.220703125e-4f, mc, t1);                          // -2^-13
                    int slot = mt * 4 + r;
                    if (d < bestd[slot]) {
                        bestd[slot] = d;
                        besti[slot] = ct * 32 + nt * 16 + cl;
                    }
                }
        __syncthreads();
    }

    // ---- cross-lane reduction over the 16 code-lanes (lex (d, idx) min) ----
#pragma unroll
    for (int slot = 0; slot < 8; ++slot) {
        float d = bestd[slot];
        int   i = besti[slot];
#pragma unroll
        for (int off = 1; off < 16; off <<= 1) {
            float od = __shfl_xor(d, off, 64);
            int   oi = __shfl_xor(i, off, 64);
            if (od < d || (od == d && oi < i)) { d = od; i = oi; }
        }
        if (cl == 0)
            out_idx[wavetok0 + (slot >> 2) * 16 + q * 4 + (slot & 3)] = i;
    }
}

// ---------- kernel 4: gather + straight-through output + loss partials ----------
// atomic spread over 128 accumulators (cut same-address f64 atomic chain
// from 16384 deep to ~128; non-argmin tail 236us -> ~100us).
__global__ __launch_bounds__(256) void finalize_kernel(
    const float* __restrict__ X, const float* __restrict__ W,
    const int* __restrict__ idx, float* __restrict__ outQ,
    float* __restrict__ outI, double* __restrict__ accum) {
    __shared__ double wsum[4];
    int wid  = threadIdx.x >> 6;
    int lane = threadIdx.x & 63;
    int token = blockIdx.x * 4 + wid;
    int id = idx[token];
    float4 x = ((const float4*)(X + (size_t)token * DIM))[lane];
    float4 qv = ((const float4*)(W + (size_t)id * DIM))[lane];
    float4 o;
    o.x = x.x + (qv.x - x.x);
    o.y = x.y + (qv.y - x.y);
    o.z = x.z + (qv.z - x.z);
    o.w = x.w + (qv.w - x.w);
    ((float4*)(outQ + (size_t)token * DIM))[lane] = o;
    float dx = x.x - qv.x, dy = x.y - qv.y, dz = x.z - qv.z, dw = x.w - qv.w;
    float s = dx * dx + dy * dy + dz * dz + dw * dw;
#pragma unroll
    for (int off = 32; off; off >>= 1) s += __shfl_down(s, off, 64);
    if (lane == 0) {
        outI[token] = (float)id;
        wsum[wid] = (double)s;
    }
    __syncthreads();
    if (threadIdx.x == 0) {
        double t = wsum[0] + wsum[1] + wsum[2] + wsum[3];
        atomicAdd(&accum[blockIdx.x & 127], t);
    }
}

// ---------- kernel 5: scalars ----------
__global__ void scalars_kernel(const double* __restrict__ accum, float* __restrict__ out) {
    double mse = 0.0;
    for (int i = 0; i < 128; ++i) mse += accum[i];
    mse /= (double)((size_t)N_TOK * DIM);
    float c = (float)mse;
    out[0] = c + 0.25f * c;
    out[1] = c;
    out[2] = c;
}

extern "C" void kernel_launch(void* const* d_in, const int* in_sizes, int n_in,
                              void* d_out, int out_size, void* d_ws, size_t ws_size,
                              hipStream_t stream) {
    const float* X = (const float*)d_in[0];   // (65536, 256)
    const float* W = (const float*)d_in[1];   // (8192, 256)

    float* outQ = (float*)d_out;
    float* outI = outQ + (size_t)N_TOK * DIM;
    float* outS = outI + N_TOK;

    char* ws = (char*)d_ws;
    double* accum = (double*)ws;                         // @0, 1 KB (128 doubles)
    float* esq = (float*)(ws + 4096);                    // 32 KB
    int*   idx = (int*)(ws + 4096 + 32768);              // 256 KB
    f16*   W1t = (f16*)(ws + (1 << 20));                 // 4 MB (k-major)
    f16*   W2t = (f16*)(ws + (1 << 20) + 4194304);       // 4 MB (k-major)

    hipMemsetAsync(accum, 0, 128 * sizeof(double), stream);
    splitw_t_kernel<<<N_CODE * 32 / 256, 256, 0, stream>>>(W, W1t, W2t);
    rowsq_kernel<<<N_CODE / 4, 256, 0, stream>>>(W, esq, N_CODE);
    argmin_mfma12<<<N_TOK / 128, 256, 0, stream>>>(X, W1t, W2t, esq, idx);
    finalize_kernel<<<N_TOK / 4, 256, 0, stream>>>(X, W, idx, outQ, outI, accum);
    scalars_kernel<<<1, 1, 0, stream>>>(accum, outS);
}

// Round 11
// 766.243 us; speedup vs baseline: 1.0121x; 1.0121x over previous
//
#include <hip/hip_runtime.h>

#define N_TOK  65536
#define N_CODE 8192
#define DIM    256

typedef _Float16 f16;
typedef _Float16 f16x8 __attribute__((ext_vector_type(8)));
typedef float    f32x4 __attribute__((ext_vector_type(4)));

// ---------- kernel 1: row sum-of-squares, W and X in ONE grid ----------
// rows 0..8191 -> W/esq; rows 8192.. -> X/sxq. Per-row code identical to the
// original rowsq (float4 lane load + shfl_down tree) — bit-identical outputs.
// NOTE: summation order bit-matches the reference fp32 reduction — do not change.
__global__ __launch_bounds__(256) void rowsq2_kernel(const float* __restrict__ W,
                                                     const float* __restrict__ X,
                                                     float* __restrict__ esq,
                                                     float* __restrict__ sxq) {
    int row  = blockIdx.x * 4 + (threadIdx.x >> 6);
    int lane = threadIdx.x & 63;
    const float* src;
    float* dst;
    if (row < N_CODE) { src = W + (size_t)row * DIM;            dst = esq + row; }
    else              { src = X + (size_t)(row - N_CODE) * DIM; dst = sxq + (row - N_CODE); }
    float4 v = ((const float4*)src)[lane];
    float s = v.x * v.x + v.y * v.y + v.z * v.z + v.w * v.w;
#pragma unroll
    for (int off = 32; off; off >>= 1) s += __shfl_down(s, off, 64);
    if (lane == 0) *dst = s;
}

// ---------- kernel 2: split W into 2 fp16 limbs, TRANSPOSED (k-major) ----------
// W1t/W2t layout: 16B granule (o, c) at byte o*131072 + c*16 holds
// W?[c][o*8 .. o*8+7]  (o = dim-octet 0..31, c = code 0..8191).
// Also zeroes the 128 loss accumulators (replaces the hipMemsetAsync dispatch;
// runs strictly before finalize in the serial stream).
__global__ __launch_bounds__(256) void splitw_t_kernel(const float* __restrict__ W,
                                                       f16* __restrict__ W1t,
                                                       f16* __restrict__ W2t,
                                                       double* __restrict__ accum) {
    if (blockIdx.x == 0 && threadIdx.x < 128) accum[threadIdx.x] = 0.0;
    int g = blockIdx.x * 256 + threadIdx.x;   // octet-task id, < 32*8192
    int o = g >> 13;                          // dim octet 0..31
    int c = g & 8191;                         // code
    const float* p = W + (size_t)c * DIM + o * 8;
    float4 v0 = ((const float4*)p)[0];
    float4 v1 = ((const float4*)p)[1];
    float e[8] = {v0.x, v0.y, v0.z, v0.w, v1.x, v1.y, v1.z, v1.w};
    union { f16 h[8]; uint4 u; } p1, p2;
#pragma unroll
    for (int i = 0; i < 8; ++i) {
        float ws = e[i] * 16384.0f;                  // exact (pow2)
        f16 w1 = (f16)ws;                            // RNE
        float r = (ws - (float)w1) * 2048.0f;        // exact
        p1.h[i] = w1; p2.h[i] = (f16)r;
    }
    size_t byteoff = (size_t)o * 131072 + (size_t)c * 16;
    *(uint4*)((char*)W1t + byteoff) = p1.u;
    *(uint4*)((char*)W2t + byteoff) = p2.u;
}

// ---------- kernel 3: fused MFMA GEMM + argmin, v8 body VERBATIM (639us) ----------
// 512 blocks x 256 thr, 2 blocks/CU, 32-code tiles, k-major conflict-free LDS,
// 16x16x32, explicit acc zero-init, separate sxq input.
// Family record: v5(conflict-free via scatter)=730, v7(VALU diet)=649,
// v9(4 domains)=742, v10(lambda pingpong)=1543, v11(macro interleave)=658,
// v12(fusion+Zseed)=673. v8=639 is the optimum; body frozen.
__global__ __launch_bounds__(256, 2) void argmin_mfma8(
    const float* __restrict__ X, const f16* __restrict__ W1t, const f16* __restrict__ W2t,
    const float* __restrict__ sxq, const float* __restrict__ esq,
    int* __restrict__ out_idx) {

    __shared__ char wbuf[65536];   // [sel:2][limb:2][o:32][c:32]*16B

    const int tid  = threadIdx.x;
    const int lane = tid & 63;
    const int wv   = tid >> 6;        // 0..3
    const int cl   = lane & 15;       // code-col / token-row within 16
    const int q    = lane >> 4;       // 0..3 k-octet
    const int l5   = lane >> 5;       // 0..1
    const int lane31 = lane & 31;
    const int wavetok0 = blockIdx.x * 128 + wv * 32;

    // ---- A: load 32 tokens x 256 dims, split to 2 f16 limbs, keep in regs ----
    // frag (mt, s): lane holds X[wavetok0 + mt*16 + cl][s*32 + q*8 + j], j=0..7
    f16x8 a1[2][8], a2[2][8];
#pragma unroll
    for (int mt = 0; mt < 2; ++mt)
#pragma unroll
        for (int s = 0; s < 8; ++s) {
            const float* p = X + (size_t)(wavetok0 + mt * 16 + cl) * DIM + s * 32 + q * 8;
            float4 v0 = ((const float4*)p)[0];
            float4 v1 = ((const float4*)p)[1];
            float e[8] = {v0.x, v0.y, v0.z, v0.w, v1.x, v1.y, v1.z, v1.w};
#pragma unroll
            for (int j = 0; j < 8; ++j) {
                f16 h = (f16)e[j];
                float r = (e[j] - (float)h) * 2048.0f;   // exact
                a1[mt][s][j] = h;
                a2[mt][s][j] = (f16)r;
            }
        }

    // sx for this lane's 8 token slots: slot = mt*4+r -> token mt*16 + q*4 + r
    float sxr[8];
#pragma unroll
    for (int mt = 0; mt < 2; ++mt)
#pragma unroll
        for (int r = 0; r < 4; ++r)
            sxr[mt * 4 + r] = sxq[wavetok0 + mt * 16 + q * 4 + r];

    float bestd[8];
    int   besti[8];
#pragma unroll
    for (int i = 0; i < 8; ++i) { bestd[i] = 3.4e38f; besti[i] = 0x7fffffff; }

    // ---- per-lane address constants ----
    const int SLB = l5 * 131072 + lane31 * 16;     // staging source lane part
    const char* RB = wbuf + q * 512 + cl * 16;     // read base (o=s*4+q, c=cl)

    // ---- staging: 32KB per ct (2 limbs x 32 octet-slabs x 512B), 32 wave-
    // instrs, 8/wave. instr fi = wv*8+t: L = fi>>4, octet pair op = fi&15.
    auto stage = [&](int ct2, int sel) {
        const char* g1 = (const char*)W1t + ct2 * 512 + SLB;
        const char* g2 = (const char*)W2t + ct2 * 512 + SLB;
#pragma unroll
        for (int t = 0; t < 8; ++t) {
            int fi = wv * 8 + t;
            int L  = fi >> 4;             // limb (wave-uniform)
            int op = fi & 15;             // octet pair (wave-uniform)
            const char* gsrc = (L ? g2 : g1) + op * 262144;
            char* ldst = wbuf + sel * 32768 + L * 16384 + op * 1024;
            __builtin_amdgcn_global_load_lds(
                (const __attribute__((address_space(1))) unsigned int*)gsrc,
                (__attribute__((address_space(3))) unsigned int*)ldst, 16, 0, 0);
        }
    };

    stage(0, 0);
    __syncthreads();

    for (int ct = 0; ct < N_CODE / 32; ++ct) {
        if (ct + 1 < N_CODE / 32) stage(ct + 1, (ct + 1) & 1);

        float se0 = esq[ct * 32 + cl];
        float se1 = esq[ct * 32 + 16 + cl];

        f32x4 mainA[2][2], cross[2][2];
#pragma unroll
        for (int mt = 0; mt < 2; ++mt)
#pragma unroll
            for (int nt = 0; nt < 2; ++nt) {
                mainA[mt][nt] = (f32x4){0.f, 0.f, 0.f, 0.f};
                cross[mt][nt] = (f32x4){0.f, 0.f, 0.f, 0.f};
            }

        const char* va = RB + ((ct & 1) << 15);
#pragma unroll
        for (int s = 0; s < 8; ++s) {
            // all 4 fragments: one vaddr + compile-time immediates
            f16x8 b1[2], b2[2];
            b1[0] = *(const f16x8*)(va + s * 2048);
            b1[1] = *(const f16x8*)(va + s * 2048 + 256);
            b2[0] = *(const f16x8*)(va + s * 2048 + 16384);
            b2[1] = *(const f16x8*)(va + s * 2048 + 16640);
            __builtin_amdgcn_s_setprio(1);
#pragma unroll
            for (int mt = 0; mt < 2; ++mt)
#pragma unroll
                for (int nt = 0; nt < 2; ++nt) {
                    mainA[mt][nt] = __builtin_amdgcn_mfma_f32_16x16x32_f16(a1[mt][s], b1[nt], mainA[mt][nt], 0, 0, 0);
                    cross[mt][nt] = __builtin_amdgcn_mfma_f32_16x16x32_f16(a2[mt][s], b1[nt], cross[mt][nt], 0, 0, 0);
                    cross[mt][nt] = __builtin_amdgcn_mfma_f32_16x16x32_f16(a1[mt][s], b2[nt], cross[mt][nt], 0, 0, 0);
                }
            __builtin_amdgcn_s_setprio(0);
        }

        // epilogue: d = fl(fl(sx+se) - 2*dot); dot*2^14 = main + 2^-11*cross
        // per lane, candidates ascend in code (nt inner, ct outer): strict < keeps lowest.
#pragma unroll
        for (int mt = 0; mt < 2; ++mt)
#pragma unroll
            for (int nt = 0; nt < 2; ++nt)
#pragma unroll
                for (int r = 0; r < 4; ++r) {
                    float mc = fmaf(cross[mt][nt][r], 4.8828125e-4f, mainA[mt][nt][r]);  // *2^-11
                    float t1 = sxr[mt * 4 + r] + (nt ? se1 : se0);
                    float d  = fmaf(-1.220703125e-4f, mc, t1);                          // -2^-13
                    int slot = mt * 4 + r;
                    if (d < bestd[slot]) {
                        bestd[slot] = d;
                        besti[slot] = ct * 32 + nt * 16 + cl;
                    }
                }
        __syncthreads();
    }

    // ---- cross-lane reduction over the 16 code-lanes (lex (d, idx) min) ----
#pragma unroll
    for (int slot = 0; slot < 8; ++slot) {
        float d = bestd[slot];
        int   i = besti[slot];
#pragma unroll
        for (int off = 1; off < 16; off <<= 1) {
            float od = __shfl_xor(d, off, 64);
            int   oi = __shfl_xor(i, off, 64);
            if (od < d || (od == d && oi < i)) { d = od; i = oi; }
        }
        if (cl == 0)
            out_idx[wavetok0 + (slot >> 2) * 16 + q * 4 + (slot & 3)] = i;
    }
}

// ---------- kernel 4: gather + straight-through output + loss partials ----------
// atomic spread over 128 accumulators (cut same-address f64 atomic chain
// from 16384 deep to ~128; non-argmin tail 236us -> ~100us).
__global__ __launch_bounds__(256) void finalize_kernel(
    const float* __restrict__ X, const float* __restrict__ W,
    const int* __restrict__ idx, float* __restrict__ outQ,
    float* __restrict__ outI, double* __restrict__ accum) {
    __shared__ double wsum[4];
    int wid  = threadIdx.x >> 6;
    int lane = threadIdx.x & 63;
    int token = blockIdx.x * 4 + wid;
    int id = idx[token];
    float4 x = ((const float4*)(X + (size_t)token * DIM))[lane];
    float4 qv = ((const float4*)(W + (size_t)id * DIM))[lane];
    float4 o;
    o.x = x.x + (qv.x - x.x);
    o.y = x.y + (qv.y - x.y);
    o.z = x.z + (qv.z - x.z);
    o.w = x.w + (qv.w - x.w);
    ((float4*)(outQ + (size_t)token * DIM))[lane] = o;
    float dx = x.x - qv.x, dy = x.y - qv.y, dz = x.z - qv.z, dw = x.w - qv.w;
    float s = dx * dx + dy * dy + dz * dz + dw * dw;
#pragma unroll
    for (int off = 32; off; off >>= 1) s += __shfl_down(s, off, 64);
    if (lane == 0) {
        outI[token] = (float)id;
        wsum[wid] = (double)s;
    }
    __syncthreads();
    if (threadIdx.x == 0) {
        double t = wsum[0] + wsum[1] + wsum[2] + wsum[3];
        atomicAdd(&accum[blockIdx.x & 127], t);
    }
}

// ---------- kernel 5: scalars ----------
__global__ void scalars_kernel(const double* __restrict__ accum, float* __restrict__ out) {
    double mse = 0.0;
    for (int i = 0; i < 128; ++i) mse += accum[i];
    mse /= (double)((size_t)N_TOK * DIM);
    float c = (float)mse;
    out[0] = c + 0.25f * c;
    out[1] = c;
    out[2] = c;
}

extern "C" void kernel_launch(void* const* d_in, const int* in_sizes, int n_in,
                              void* d_out, int out_size, void* d_ws, size_t ws_size,
                              hipStream_t stream) {
    const float* X = (const float*)d_in[0];   // (65536, 256)
    const float* W = (const float*)d_in[1];   // (8192, 256)

    float* outQ = (float*)d_out;
    float* outI = outQ + (size_t)N_TOK * DIM;
    float* outS = outI + N_TOK;

    char* ws = (char*)d_ws;
    double* accum = (double*)ws;                         // @0, 1 KB (128 doubles)
    float* esq = (float*)(ws + 4096);                    // 32 KB
    float* sxq = (float*)(ws + 4096 + 32768);            // 256 KB
    int*   idx = (int*)(ws + 4096 + 32768 + 262144);     // 256 KB
    f16*   W1t = (f16*)(ws + (1 << 20));                 // 4 MB (k-major)
    f16*   W2t = (f16*)(ws + (1 << 20) + 4194304);       // 4 MB (k-major)

    splitw_t_kernel<<<N_CODE * 32 / 256, 256, 0, stream>>>(W, W1t, W2t, accum);
    rowsq2_kernel<<<(N_CODE + N_TOK) / 4, 256, 0, stream>>>(W, X, esq, sxq);
    argmin_mfma8<<<N_TOK / 128, 256, 0, stream>>>(X, W1t, W2t, sxq, esq, idx);
    finalize_kernel<<<N_TOK / 4, 256, 0, stream>>>(X, W, idx, outQ, outI, accum);
    scalars_kernel<<<1, 1, 0, stream>>>(accum, outS);
}

// Round 12
// 757.136 us; speedup vs baseline: 1.0243x; 1.0120x over previous
//
#include <hip/hip_runtime.h>

#define N_TOK  65536
#define N_CODE 8192
#define DIM    256

typedef _Float16 f16;
typedef _Float16 f16x8 __attribute__((ext_vector_type(8)));
typedef float    f32x4 __attribute__((ext_vector_type(4)));

// ---------- kernel 1: prep = splitw (k-major limbs) + rowsq(W->esq, X->sxq) ----------
// blocks 0..1023: split W into 2 fp16 limbs, TRANSPOSED (k-major).
//   W1t/W2t layout: 16B granule (o, c) at byte o*131072 + c*16 holds
//   W?[c][o*8..o*8+7] (o = dim-octet 0..31, c = code 0..8191). Block 0 also
//   zeroes the 128 loss accumulators (stream-ordered before argmin's atomics).
// blocks 1024..: row sum-of-squares, rows 0..8191 -> W/esq, 8192.. -> X/sxq.
//   NOTE: float4 lane load + shfl_down tree bit-matches the reference fp32
//   reduction — do not change.
__global__ __launch_bounds__(256) void prep_kernel(const float* __restrict__ W,
                                                   const float* __restrict__ X,
                                                   f16* __restrict__ W1t,
                                                   f16* __restrict__ W2t,
                                                   float* __restrict__ esq,
                                                   float* __restrict__ sxq,
                                                   double* __restrict__ accum) {
    if (blockIdx.x < 1024) {
        if (blockIdx.x == 0 && threadIdx.x < 128) accum[threadIdx.x] = 0.0;
        int g = blockIdx.x * 256 + threadIdx.x;   // octet-task id, < 32*8192
        int o = g >> 13;                          // dim octet 0..31
        int c = g & 8191;                         // code
        const float* p = W + (size_t)c * DIM + o * 8;
        float4 v0 = ((const float4*)p)[0];
        float4 v1 = ((const float4*)p)[1];
        float e[8] = {v0.x, v0.y, v0.z, v0.w, v1.x, v1.y, v1.z, v1.w};
        union { f16 h[8]; uint4 u; } p1, p2;
#pragma unroll
        for (int i = 0; i < 8; ++i) {
            float ws = e[i] * 16384.0f;                  // exact (pow2)
            f16 w1 = (f16)ws;                            // RNE
            float r = (ws - (float)w1) * 2048.0f;        // exact
            p1.h[i] = w1; p2.h[i] = (f16)r;
        }
        size_t byteoff = (size_t)o * 131072 + (size_t)c * 16;
        *(uint4*)((char*)W1t + byteoff) = p1.u;
        *(uint4*)((char*)W2t + byteoff) = p2.u;
    } else {
        int row  = (blockIdx.x - 1024) * 4 + (threadIdx.x >> 6);
        int lane = threadIdx.x & 63;
        const float* src;
        float* dst;
        if (row < N_CODE) { src = W + (size_t)row * DIM;            dst = esq + row; }
        else              { src = X + (size_t)(row - N_CODE) * DIM; dst = sxq + (row - N_CODE); }
        float4 v = ((const float4*)src)[lane];
        float s = v.x * v.x + v.y * v.y + v.z * v.z + v.w * v.w;
#pragma unroll
        for (int off = 32; off; off >>= 1) s += __shfl_down(s, off, 64);
        if (lane == 0) *dst = s;
    }
}

// ---------- kernel 2: fused MFMA GEMM + argmin + finalize ----------
// Main loop: v8 body VERBATIM (best of family; v5/v7/v9/v10/v11/v12 all
// null-to-negative; cross-session clock drift ~3% — do not touch).
// 512 blocks x 256 thr, 2 blocks/CU, 32-code tiles, k-major conflict-free
// LDS, 16x16x32, explicit acc zero-init.
// v13: finalize FUSED into the tail. After the xor-butterfly reduction every
// lane holds its group's winning idx; each wave gathers W[id], writes
// outQ/outI and accumulates the loss for its 32 tokens (per-token s uses the
// finalize-verbatim float tree -> bit-exact; double-sum grouping differs but
// atomic arrival order was already nondeterministic: ~1e-16 wobble vs the
// 1e-7 float-cast grid). Deletes the finalize dispatch + idx round-trip;
// X re-read largely L3-resident.
__global__ __launch_bounds__(256, 2) void argmin_mfma13(
    const float* __restrict__ X, const float* __restrict__ W,
    const f16* __restrict__ W1t, const f16* __restrict__ W2t,
    const float* __restrict__ sxq, const float* __restrict__ esq,
    float* __restrict__ outQ, float* __restrict__ outI,
    double* __restrict__ accum) {

    __shared__ char wbuf[65536];   // [sel:2][limb:2][o:32][c:32]*16B

    const int tid  = threadIdx.x;
    const int lane = tid & 63;
    const int wv   = tid >> 6;        // 0..3
    const int cl   = lane & 15;       // code-col / token-row within 16
    const int q    = lane >> 4;       // 0..3 k-octet
    const int l5   = lane >> 5;       // 0..1
    const int lane31 = lane & 31;
    const int wavetok0 = blockIdx.x * 128 + wv * 32;

    // ---- A: load 32 tokens x 256 dims, split to 2 f16 limbs, keep in regs ----
    // frag (mt, s): lane holds X[wavetok0 + mt*16 + cl][s*32 + q*8 + j], j=0..7
    f16x8 a1[2][8], a2[2][8];
#pragma unroll
    for (int mt = 0; mt < 2; ++mt)
#pragma unroll
        for (int s = 0; s < 8; ++s) {
            const float* p = X + (size_t)(wavetok0 + mt * 16 + cl) * DIM + s * 32 + q * 8;
            float4 v0 = ((const float4*)p)[0];
            float4 v1 = ((const float4*)p)[1];
            float e[8] = {v0.x, v0.y, v0.z, v0.w, v1.x, v1.y, v1.z, v1.w};
#pragma unroll
            for (int j = 0; j < 8; ++j) {
                f16 h = (f16)e[j];
                float r = (e[j] - (float)h) * 2048.0f;   // exact
                a1[mt][s][j] = h;
                a2[mt][s][j] = (f16)r;
            }
        }

    // sx for this lane's 8 token slots: slot = mt*4+r -> token mt*16 + q*4 + r
    float sxr[8];
#pragma unroll
    for (int mt = 0; mt < 2; ++mt)
#pragma unroll
        for (int r = 0; r < 4; ++r)
            sxr[mt * 4 + r] = sxq[wavetok0 + mt * 16 + q * 4 + r];

    float bestd[8];
    int   besti[8];
#pragma unroll
    for (int i = 0; i < 8; ++i) { bestd[i] = 3.4e38f; besti[i] = 0x7fffffff; }

    // ---- per-lane address constants ----
    const int SLB = l5 * 131072 + lane31 * 16;     // staging source lane part
    const char* RB = wbuf + q * 512 + cl * 16;     // read base (o=s*4+q, c=cl)

    // ---- staging: 32KB per ct (2 limbs x 32 octet-slabs x 512B), 32 wave-
    // instrs, 8/wave. instr fi = wv*8+t: L = fi>>4, octet pair op = fi&15.
    auto stage = [&](int ct2, int sel) {
        const char* g1 = (const char*)W1t + ct2 * 512 + SLB;
        const char* g2 = (const char*)W2t + ct2 * 512 + SLB;
#pragma unroll
        for (int t = 0; t < 8; ++t) {
            int fi = wv * 8 + t;
            int L  = fi >> 4;             // limb (wave-uniform)
            int op = fi & 15;             // octet pair (wave-uniform)
            const char* gsrc = (L ? g2 : g1) + op * 262144;
            char* ldst = wbuf + sel * 32768 + L * 16384 + op * 1024;
            __builtin_amdgcn_global_load_lds(
                (const __attribute__((address_space(1))) unsigned int*)gsrc,
                (__attribute__((address_space(3))) unsigned int*)ldst, 16, 0, 0);
        }
    };

    stage(0, 0);
    __syncthreads();

    for (int ct = 0; ct < N_CODE / 32; ++ct) {
        if (ct + 1 < N_CODE / 32) stage(ct + 1, (ct + 1) & 1);

        float se0 = esq[ct * 32 + cl];
        float se1 = esq[ct * 32 + 16 + cl];

        f32x4 mainA[2][2], cross[2][2];
#pragma unroll
        for (int mt = 0; mt < 2; ++mt)
#pragma unroll
            for (int nt = 0; nt < 2; ++nt) {
                mainA[mt][nt] = (f32x4){0.f, 0.f, 0.f, 0.f};
                cross[mt][nt] = (f32x4){0.f, 0.f, 0.f, 0.f};
            }

        const char* va = RB + ((ct & 1) << 15);
#pragma unroll
        for (int s = 0; s < 8; ++s) {
            // all 4 fragments: one vaddr + compile-time immediates
            f16x8 b1[2], b2[2];
            b1[0] = *(const f16x8*)(va + s * 2048);
            b1[1] = *(const f16x8*)(va + s * 2048 + 256);
            b2[0] = *(const f16x8*)(va + s * 2048 + 16384);
            b2[1] = *(const f16x8*)(va + s * 2048 + 16640);
            __builtin_amdgcn_s_setprio(1);
#pragma unroll
            for (int mt = 0; mt < 2; ++mt)
#pragma unroll
                for (int nt = 0; nt < 2; ++nt) {
                    mainA[mt][nt] = __builtin_amdgcn_mfma_f32_16x16x32_f16(a1[mt][s], b1[nt], mainA[mt][nt], 0, 0, 0);
                    cross[mt][nt] = __builtin_amdgcn_mfma_f32_16x16x32_f16(a2[mt][s], b1[nt], cross[mt][nt], 0, 0, 0);
                    cross[mt][nt] = __builtin_amdgcn_mfma_f32_16x16x32_f16(a1[mt][s], b2[nt], cross[mt][nt], 0, 0, 0);
                }
            __builtin_amdgcn_s_setprio(0);
        }

        // epilogue: d = fl(fl(sx+se) - 2*dot); dot*2^14 = main + 2^-11*cross
        // per lane, candidates ascend in code (nt inner, ct outer): strict < keeps lowest.
#pragma unroll
        for (int mt = 0; mt < 2; ++mt)
#pragma unroll
            for (int nt = 0; nt < 2; ++nt)
#pragma unroll
                for (int r = 0; r < 4; ++r) {
                    float mc = fmaf(cross[mt][nt][r], 4.8828125e-4f, mainA[mt][nt][r]);  // *2^-11
                    float t1 = sxr[mt * 4 + r] + (nt ? se1 : se0);
                    float d  = fmaf(-1.220703125e-4f, mc, t1);                          // -2^-13
                    int slot = mt * 4 + r;
                    if (d < bestd[slot]) {
                        bestd[slot] = d;
                        besti[slot] = ct * 32 + nt * 16 + cl;
                    }
                }
        __syncthreads();
    }

    // ---- cross-lane reduction over the 16 code-lanes (lex (d, idx) min) ----
    // xor-butterfly: afterwards EVERY lane in a 16-group holds the group min.
    int ri[8];
#pragma unroll
    for (int slot = 0; slot < 8; ++slot) {
        float d = bestd[slot];
        int   i = besti[slot];
#pragma unroll
        for (int off = 1; off < 16; off <<= 1) {
            float od = __shfl_xor(d, off, 64);
            int   oi = __shfl_xor(i, off, 64);
            if (od < d || (od == d && oi < i)) { d = od; i = oi; }
        }
        ri[slot] = i;
    }

    // ---- fused finalize: gather + straight-through output + loss partials ----
    // token tt = mt*16 + qq*4 + r <-> (slot = mt*4+r, qq); idx lives in lane
    // qq*16 (any cl). Per-token s: finalize-verbatim float4 + shfl_down tree.
    double accw = 0.0;
#pragma unroll
    for (int slot = 0; slot < 8; ++slot)
#pragma unroll
        for (int qq = 0; qq < 4; ++qq) {
            int id = __shfl(ri[slot], qq * 16);
            int token = wavetok0 + (slot >> 2) * 16 + qq * 4 + (slot & 3);
            float4 x  = ((const float4*)(X + (size_t)token * DIM))[lane];
            float4 qv = ((const float4*)(W + (size_t)id * DIM))[lane];
            float4 o;
            o.x = x.x + (qv.x - x.x);
            o.y = x.y + (qv.y - x.y);
            o.z = x.z + (qv.z - x.z);
            o.w = x.w + (qv.w - x.w);
            ((float4*)(outQ + (size_t)token * DIM))[lane] = o;
            float dx = x.x - qv.x, dy = x.y - qv.y, dz = x.z - qv.z, dw = x.w - qv.w;
            float s = dx * dx + dy * dy + dz * dz + dw * dw;
#pragma unroll
            for (int off = 32; off; off >>= 1) s += __shfl_down(s, off, 64);
            if (lane == 0) {
                outI[token] = (float)id;
                accw += (double)s;
            }
        }
    if (lane == 0)
        atomicAdd(&accum[(blockIdx.x * 4 + wv) & 127], accw);
}

// ---------- kernel 3: scalars ----------
__global__ void scalars_kernel(const double* __restrict__ accum, float* __restrict__ out) {
    double mse = 0.0;
    for (int i = 0; i < 128; ++i) mse += accum[i];
    mse /= (double)((size_t)N_TOK * DIM);
    float c = (float)mse;
    out[0] = c + 0.25f * c;
    out[1] = c;
    out[2] = c;
}

extern "C" void kernel_launch(void* const* d_in, const int* in_sizes, int n_in,
                              void* d_out, int out_size, void* d_ws, size_t ws_size,
                              hipStream_t stream) {
    const float* X = (const float*)d_in[0];   // (65536, 256)
    const float* W = (const float*)d_in[1];   // (8192, 256)

    float* outQ = (float*)d_out;
    float* outI = outQ + (size_t)N_TOK * DIM;
    float* outS = outI + N_TOK;

    char* ws = (char*)d_ws;
    double* accum = (double*)ws;                         // @0, 1 KB (128 doubles)
    float* esq = (float*)(ws + 4096);                    // 32 KB
    float* sxq = (float*)(ws + 4096 + 32768);            // 256 KB
    f16*   W1t = (f16*)(ws + (1 << 20));                 // 4 MB (k-major)
    f16*   W2t = (f16*)(ws + (1 << 20) + 4194304);       // 4 MB (k-major)

    prep_kernel<<<1024 + (N_CODE + N_TOK) / 4, 256, 0, stream>>>(W, X, W1t, W2t, esq, sxq, accum);
    argmin_mfma13<<<N_TOK / 128, 256, 0, stream>>>(X, W, W1t, W2t, sxq, esq, outQ, outI, accum);
    scalars_kernel<<<1, 1, 0, stream>>>(accum, outS);
}